// Round 3
// baseline (191.794 us; speedup 1.0000x reference)
//
#include <hip/hip_runtime.h>
#include <hip/hip_fp16.h>
#include <math.h>

typedef _Float16 f16;
typedef __attribute__((ext_vector_type(8))) _Float16 f16x8;
typedef __attribute__((ext_vector_type(4))) _Float16 f16x4;
typedef __attribute__((ext_vector_type(4))) float f32x4;
typedef __attribute__((ext_vector_type(16))) float f32x16;

#define NB 16
#define NN 2048
#define ND 256
#define KVB 32
#define QW 32   // q rows per wave (= per block) in attn3

__device__ __forceinline__ void gll16(const void* g, void* l) {
    __builtin_amdgcn_global_load_lds(
        (const __attribute__((address_space(1))) unsigned int*)g,
        (__attribute__((address_space(3))) unsigned int*)l, 16, 0, 0);
}

__device__ __forceinline__ long long len_at(const int* lenp, int b, bool is64) {
    return is64 ? ((const long long*)lenp)[b] : (long long)lenp[b];
}

// ---------------- pre-pass: X fp32 -> Xh f16 [b][n][d] + Xt f16 [b][d][n] ----
__global__ __launch_bounds__(256)
void prep(const float* __restrict__ X, f16* __restrict__ Xh, f16* __restrict__ Xt)
{
    const int b  = blockIdx.z;
    const int n0 = blockIdx.x * 64;
    const int d0 = blockIdx.y * 64;
    const int t  = threadIdx.x;
    __shared__ f16 T[64][72];

    const float* Xb  = X  + ((size_t)b*NN + n0)*ND + d0;
    f16*         Xhb = Xh + ((size_t)b*NN + n0)*ND + d0;
    #pragma unroll
    for (int it = 0; it < 4; ++it) {
        int r  = it*16 + (t >> 4);
        int c4 = t & 15;
        float4 v = *(const float4*)(Xb + (size_t)r*ND + c4*4);
        f16x4 h; h[0]=(f16)v.x; h[1]=(f16)v.y; h[2]=(f16)v.z; h[3]=(f16)v.w;
        *(f16x4*)&Xhb[(size_t)r*ND + c4*4] = h;
        *(f16x4*)&T[r][c4*4] = h;
    }
    __syncthreads();
    f16* Xtb = Xt + ((size_t)b*ND + d0)*NN + n0;
    #pragma unroll
    for (int it = 0; it < 2; ++it) {
        int id = it*256 + t;
        int dr = id >> 3;
        int ch = id & 7;
        f16x8 v;
        #pragma unroll
        for (int u = 0; u < 8; ++u) v[u] = T[ch*8+u][dr];
        *(f16x8*)&Xtb[(size_t)dr*NN + ch*8] = v;
    }
}

// ---------------- main: 1-wave blocks, 32x32x16 swapped-operand flash ------
__global__ __launch_bounds__(64, 1)
void attn3(const f16* __restrict__ Xh, const f16* __restrict__ Xt,
           const int* __restrict__ lenp, float* __restrict__ out)
{
    const int l   = threadIdx.x;     // 0..63
    const int r31 = l & 31;
    const int h   = l >> 5;

    // bit-reversed rank (10 bits) -> any co-resident group of blocks gets a
    // stratified slice of the length-sorted work list
    const unsigned lin = blockIdx.x;
    const unsigned rank = __brev(lin) >> 22;

    // in-register selection of the batch at sorted-desc position (rank>>6)
    const bool is64 = (lenp[1] == 0);
    long long Lv[NB];
    #pragma unroll
    for (int i = 0; i < NB; ++i) Lv[i] = len_at(lenp, i, is64);
    const int pos = (int)(rank >> 6);
    int bsel = 0; long long Lb = Lv[0];
    #pragma unroll
    for (int bb = 0; bb < NB; ++bb) {
        int rk = 0;
        #pragma unroll
        for (int b2 = 0; b2 < NB; ++b2)
            rk += (Lv[b2] > Lv[bb]) || (Lv[b2] == Lv[bb] && b2 < bb);
        if (rk == pos) { bsel = bb; Lb = Lv[bb]; }
    }
    const int qt = (int)(rank & 63);
    const int q0 = qt * QW;
    const int nt = (int)((Lb + KVB - 1) / KVB);

    __shared__ f16 Kl[KVB][256];   // 16KB: [j][d], 16B-slot u XOR (j&7)
    __shared__ f16 Vt[ND][32];     // 16KB: [d][j], 16B-slot u XOR (d&3)

    const char* xhb = (const char*)(Xh + (size_t)bsel*NN*ND);
    const char* xtb = (const char*)(Xt + (size_t)bsel*ND*NN);

    // Q B-frags: lane supplies Q[q0+r31][kk*16 + h*8 + i]
    f16x8 qf[16];
    {
        const char* qp = xhb + (size_t)(q0 + r31) * 512 + h*16;
        #pragma unroll
        for (int kk = 0; kk < 16; ++kk)
            qf[kk] = *(const f16x8*)(qp + kk*32);
    }

    f32x16 o[8];
    #pragma unroll
    for (int dt = 0; dt < 8; ++dt)
        #pragma unroll
        for (int r = 0; r < 16; ++r) o[dt][r] = 0.f;
    float m = -INFINITY, lsum = 0.f;

    // ---- staging: linear LDS dest (lane*16), inverse-swizzled global src ----
    auto stage_k = [&](int kv0) {
        #pragma unroll
        for (int it = 0; it < 16; ++it) {
            int slot = it*1024 + l*16;
            int r = slot >> 9;              // j row 0..31
            int u = (slot >> 4) & 31;       // 16B slot in row
            gll16(xhb + (((size_t)kv0 + r) << 9) + ((size_t)(u ^ (r & 7)) << 4),
                  (char*)&Kl[0][0] + slot);
        }
    };
    auto stage_v = [&](int kv0) {
        #pragma unroll
        for (int it = 0; it < 16; ++it) {
            int slot = it*1024 + l*16;
            int r = slot >> 6;              // d row 0..255
            int u = (slot >> 4) & 3;        // 16B slot in row
            gll16(xtb + ((size_t)r << 12) + (((size_t)kv0 + ((u ^ (r & 3)) << 3)) << 1),
                  (char*)&Vt[0][0] + slot);
        }
    };

    stage_k(0);
    stage_v(0);

    for (int t = 0; t < nt; ++t) {
        const int kv0 = t * KVB;

        // K(t) ready: outstanding = K(t)[16] + V(t)[16] -> drain older 16
        asm volatile("s_waitcnt vmcnt(16)" ::: "memory");
        __builtin_amdgcn_sched_barrier(0);

        // ---- QK^T (swapped): St[j][q] = K . Q^T, two interleaved chains ----
        f32x16 sa, sb;
        #pragma unroll
        for (int r = 0; r < 16; ++r) { sa[r] = 0.f; sb[r] = 0.f; }
        const char* kb = (const char*)&Kl[0][0];
        #pragma unroll
        for (int kk = 0; kk < 16; kk += 2) {
            f16x8 a0 = *(const f16x8*)(kb + r31*512 + ((( kk   *2 + h) ^ (r31 & 7)) << 4));
            f16x8 a1 = *(const f16x8*)(kb + r31*512 + ((((kk+1)*2 + h) ^ (r31 & 7)) << 4));
            sa = __builtin_amdgcn_mfma_f32_32x32x16_f16(a0, qf[kk],   sa, 0, 0, 0);
            sb = __builtin_amdgcn_mfma_f32_32x32x16_f16(a1, qf[kk+1], sb, 0, 0, 0);
        }
        f32x16 st = sa + sb;

        // K reads returned -> safe to overwrite K region with next tile
        asm volatile("s_waitcnt lgkmcnt(0)" ::: "memory");
        __builtin_amdgcn_sched_barrier(0);
        if (t + 1 < nt) stage_k(kv0 + KVB);

        // ---- column mask (last tile only) ----
        if (kv0 + KVB > (int)Lb) {
            #pragma unroll
            for (int r = 0; r < 16; ++r) {
                int j = (r & 3) + 8 * (r >> 2) + 4*h;
                if (kv0 + j >= (int)Lb) st[r] = -1e30f;
            }
        }

        // ---- online softmax: lane owns half of row q=r31; partner = l^32 ----
        float tm = st[0];
        #pragma unroll
        for (int r = 1; r < 16; ++r) tm = fmaxf(tm, st[r]);
        tm = fmaxf(tm, __shfl_xor(tm, 32, 64));
        if (!__all(tm <= m + 8.f)) {          // defer-max THR=8
            float nm = fmaxf(m, tm);
            float sc = __expf(m - nm);
            #pragma unroll
            for (int dt = 0; dt < 8; ++dt)
                #pragma unroll
                for (int r = 0; r < 16; ++r) o[dt][r] *= sc;
            lsum *= sc;
            m = nm;
        }
        float p[16];
        float rs = 0.f;
        #pragma unroll
        for (int r = 0; r < 16; ++r) { p[r] = __expf(st[r] - m); rs += p[r]; }
        rs += __shfl_xor(rs, 32, 64);
        lsum += rs;

        // ---- pack P to f16 quads, redistribute to PV B-frag layout ----
        unsigned q[8];
        #pragma unroll
        for (int qi = 0; qi < 4; ++qi) {
            f16x4 hp;
            hp[0]=(f16)p[4*qi+0]; hp[1]=(f16)p[4*qi+1];
            hp[2]=(f16)p[4*qi+2]; hp[3]=(f16)p[4*qi+3];
            q[2*qi]   = ((unsigned*)&hp)[0];
            q[2*qi+1] = ((unsigned*)&hp)[1];
        }
        unsigned sq[8];
        #pragma unroll
        for (int i = 0; i < 8; ++i) sq[i] = __shfl_xor(q[i], 32, 64);
        union { unsigned u[4]; f16x8 v; } pf0, pf1;
        pf0.u[0] = h ? sq[2] : q[0];
        pf0.u[1] = h ? sq[3] : q[1];
        pf0.u[2] = h ? q[2]  : sq[0];
        pf0.u[3] = h ? q[3]  : sq[1];
        pf1.u[0] = h ? sq[6] : q[4];
        pf1.u[1] = h ? sq[7] : q[5];
        pf1.u[2] = h ? q[6]  : sq[4];
        pf1.u[3] = h ? q[7]  : sq[5];

        // V(t) ready
        if (t + 1 < nt) { asm volatile("s_waitcnt vmcnt(16)" ::: "memory"); }
        else            { asm volatile("s_waitcnt vmcnt(0)"  ::: "memory"); }
        __builtin_amdgcn_sched_barrier(0);

        // ---- PV (swapped): O^T[d][q] += V^T . P^T ----
        const char* vb = (const char*)&Vt[0][0];
        #pragma unroll
        for (int dt = 0; dt < 8; ++dt) {
            int rr = dt*32 + r31;
            f16x8 v0 = *(const f16x8*)(vb + rr*64 + (((0 + h) ^ (r31 & 3)) << 4));
            f16x8 v1 = *(const f16x8*)(vb + rr*64 + (((2 + h) ^ (r31 & 3)) << 4));
            o[dt] = __builtin_amdgcn_mfma_f32_32x32x16_f16(v0, pf0.v, o[dt], 0, 0, 0);
            o[dt] = __builtin_amdgcn_mfma_f32_32x32x16_f16(v1, pf1.v, o[dt], 0, 0, 0);
        }

        // V reads returned -> safe to overwrite V region with next tile
        asm volatile("s_waitcnt lgkmcnt(0)" ::: "memory");
        __builtin_amdgcn_sched_barrier(0);
        if (t + 1 < nt) stage_v(kv0 + KVB);
    }

    // ---- epilogue: normalize + store (float4 per reg-quad) ----
    float inv = 1.f / lsum;
    float* ob = out + ((size_t)bsel*NN + q0 + r31) * ND;
    #pragma unroll
    for (int dt = 0; dt < 8; ++dt) {
        #pragma unroll
        for (int g4 = 0; g4 < 4; ++g4) {
            float4 vv;
            vv.x = o[dt][g4*4+0] * inv;
            vv.y = o[dt][g4*4+1] * inv;
            vv.z = o[dt][g4*4+2] * inv;
            vv.w = o[dt][g4*4+3] * inv;
            int d = dt*32 + 8*g4 + 4*h;
            *(float4*)(ob + d) = vv;
        }
    }
}

// ---------------- fallback (round-1 kernel) if ws too small ----------------
__global__ __launch_bounds__(256, 2)
void attn_fb(const float* __restrict__ X,
             const int* __restrict__ lenp,
             float* __restrict__ out)
{
    const int b   = blockIdx.y;
    const int qt  = blockIdx.x;
    const int tid = threadIdx.x;
    const int lane = tid & 63;
    const int w = tid >> 6;
    const int g = lane >> 4;
    const int c = lane & 15;

    const bool is64 = (lenp[1] == 0);
    const long long Lb = len_at(lenp, b, is64);

    __shared__ f16 Kl[KVB][264];
    __shared__ f16 Vt2[ND][40];
    __shared__ f16 Pl[4][16][40];

    const float* Xb = X + (size_t)b * NN * ND;

    f16x8 qf[8];
    {
        const float* qp = Xb + (size_t)(qt*64 + w*16 + c) * ND + g*8;
        #pragma unroll
        for (int kk = 0; kk < 8; ++kk) {
            float4 a = *(const float4*)(qp + kk*32);
            float4 d = *(const float4*)(qp + kk*32 + 4);
            f16x8 v;
            v[0]=(f16)a.x; v[1]=(f16)a.y; v[2]=(f16)a.z; v[3]=(f16)a.w;
            v[4]=(f16)d.x; v[5]=(f16)d.y; v[6]=(f16)d.z; v[7]=(f16)d.w;
            qf[kk] = v;
        }
    }

    f32x4 o[16];
    #pragma unroll
    for (int dt = 0; dt < 16; ++dt) o[dt] = (f32x4){0.f,0.f,0.f,0.f};
    float m[4] = {-INFINITY,-INFINITY,-INFINITY,-INFINITY};
    float lr[4] = {0.f,0.f,0.f,0.f};

    const int ntiles = (int)((Lb + KVB - 1) / KVB);
    for (int t = 0; t < ntiles; ++t) {
        const int kv0 = t * KVB;
        __syncthreads();
        #pragma unroll
        for (int it = 0; it < 8; ++it) {
            int idx4 = it*256 + tid;
            int row  = idx4 >> 6;
            int c4   = idx4 & 63;
            float4 v = *(const float4*)(Xb + (size_t)(kv0 + row)*ND + c4*4);
            f16x4 hh; hh[0]=(f16)v.x; hh[1]=(f16)v.y; hh[2]=(f16)v.z; hh[3]=(f16)v.w;
            *(f16x4*)&Kl[row][c4*4] = hh;
        }
        {
            const float* cp = Xb + (size_t)kv0*ND + tid;
            #pragma unroll
            for (int kq = 0; kq < 8; ++kq) {
                f16x4 hh;
                #pragma unroll
                for (int u = 0; u < 4; ++u) hh[u] = (f16)cp[(size_t)(kq*4+u)*ND];
                *(f16x4*)&Vt2[tid][kq*4] = hh;
            }
        }
        __syncthreads();

        f32x4 s0 = (f32x4){0.f,0.f,0.f,0.f};
        f32x4 s1 = (f32x4){0.f,0.f,0.f,0.f};
        #pragma unroll
        for (int kk = 0; kk < 8; ++kk) {
            f16x8 b0 = *(const f16x8*)&Kl[c     ][kk*32 + g*8];
            f16x8 b1 = *(const f16x8*)&Kl[16 + c][kk*32 + g*8];
            s0 = __builtin_amdgcn_mfma_f32_16x16x32_f16(qf[kk], b0, s0, 0, 0, 0);
            s1 = __builtin_amdgcn_mfma_f32_16x16x32_f16(qf[kk], b1, s1, 0, 0, 0);
        }

        const float NEG = -1e30f;
        if (kv0 + c >= Lb)      { s0[0]=NEG; s0[1]=NEG; s0[2]=NEG; s0[3]=NEG; }
        if (kv0 + 16 + c >= Lb) { s1[0]=NEG; s1[1]=NEG; s1[2]=NEG; s1[3]=NEG; }

        float mx[4], mn[4], sc[4], p0[4], p1[4], rs[4];
        #pragma unroll
        for (int r = 0; r < 4; ++r) mx[r] = fmaxf(s0[r], s1[r]);
        #pragma unroll
        for (int off = 8; off >= 1; off >>= 1) {
            #pragma unroll
            for (int r = 0; r < 4; ++r)
                mx[r] = fmaxf(mx[r], __shfl_xor(mx[r], off, 64));
        }
        #pragma unroll
        for (int r = 0; r < 4; ++r) {
            mn[r] = fmaxf(m[r], mx[r]);
            sc[r] = __expf(m[r] - mn[r]);
            p0[r] = __expf(s0[r] - mn[r]);
            p1[r] = __expf(s1[r] - mn[r]);
            rs[r] = p0[r] + p1[r];
        }
        #pragma unroll
        for (int off = 8; off >= 1; off >>= 1) {
            #pragma unroll
            for (int r = 0; r < 4; ++r)
                rs[r] += __shfl_xor(rs[r], off, 64);
        }
        bool chg = (sc[0]!=1.f) | (sc[1]!=1.f) | (sc[2]!=1.f) | (sc[3]!=1.f);
        if (__any(chg)) {
            #pragma unroll
            for (int dt = 0; dt < 16; ++dt) {
                o[dt][0]*=sc[0]; o[dt][1]*=sc[1]; o[dt][2]*=sc[2]; o[dt][3]*=sc[3];
            }
        }
        #pragma unroll
        for (int r = 0; r < 4; ++r) { lr[r] = lr[r]*sc[r] + rs[r]; m[r] = mn[r]; }

        #pragma unroll
        for (int r = 0; r < 4; ++r) {
            Pl[w][g*4+r][c]      = (f16)p0[r];
            Pl[w][g*4+r][16 + c] = (f16)p1[r];
        }
        f16x8 pf = *(const f16x8*)&Pl[w][c][g*8];

        #pragma unroll
        for (int dt = 0; dt < 16; ++dt) {
            f16x8 vf = *(const f16x8*)&Vt2[dt*16 + c][g*8];
            o[dt] = __builtin_amdgcn_mfma_f32_16x16x32_f16(pf, vf, o[dt], 0, 0, 0);
        }
    }

    float inv[4];
    #pragma unroll
    for (int r = 0; r < 4; ++r) inv[r] = 1.0f / lr[r];
    float* ob = out + ((size_t)b*NN + (size_t)(qt*64 + w*16 + g*4))*ND + c;
    #pragma unroll
    for (int r = 0; r < 4; ++r) {
        #pragma unroll
        for (int dt = 0; dt < 16; ++dt)
            ob[(size_t)r*ND + dt*16] = o[dt][r] * inv[r];
    }
}

extern "C" void kernel_launch(void* const* d_in, const int* in_sizes, int n_in,
                              void* d_out, int out_size, void* d_ws, size_t ws_size,
                              hipStream_t stream) {
    const float* X    = (const float*)d_in[0];
    const int*   lenp = (const int*)d_in[1];
    float*       out  = (float*)d_out;

    const size_t need = (size_t)NB * NN * ND * 2 /*f16*/ * 2 /*Xh+Xt*/;
    if (ws_size >= need) {
        f16* Xh = (f16*)d_ws;
        f16* Xt = Xh + (size_t)NB * NN * ND;
        hipLaunchKernelGGL(prep, dim3(NN/64, ND/64, NB), dim3(256), 0, stream, X, Xh, Xt);
        hipLaunchKernelGGL(attn3, dim3(1024), dim3(64), 0, stream, Xh, Xt, lenp, out);
    } else {
        hipLaunchKernelGGL(attn_fb, dim3(NN/64, NB), dim3(256), 0, stream, X, lenp, out);
    }
}

// Round 5
// 142.509 us; speedup vs baseline: 1.3458x; 1.3458x over previous
//
#include <hip/hip_runtime.h>
#include <hip/hip_fp16.h>
#include <math.h>

typedef _Float16 f16;
typedef __attribute__((ext_vector_type(8))) _Float16 f16x8;
typedef __attribute__((ext_vector_type(4))) _Float16 f16x4;
typedef __attribute__((ext_vector_type(4))) float f32x4;

#define NB 16
#define NN 2048
#define ND 256
#define KVB 32
#define QB 64

__device__ __forceinline__ void gll16(const void* g, void* l) {
    __builtin_amdgcn_global_load_lds(
        (const __attribute__((address_space(1))) unsigned int*)g,
        (__attribute__((address_space(3))) unsigned int*)l, 16, 0, 0);
}

__device__ __forceinline__ long long len_at(const int* lenp, int b, bool is64) {
    return is64 ? ((const long long*)lenp)[b] : (long long)lenp[b];
}

// ---------------- pre-pass: X fp32 -> Xh f16 [b][n][d] + Xt f16 [b][d][n] ----
__global__ __launch_bounds__(256)
void prep(const float* __restrict__ X, f16* __restrict__ Xh, f16* __restrict__ Xt)
{
    const int b  = blockIdx.z;
    const int n0 = blockIdx.x * 64;
    const int d0 = blockIdx.y * 64;
    const int t  = threadIdx.x;
    __shared__ f16 T[64][72];

    const float* Xb  = X  + ((size_t)b*NN + n0)*ND + d0;
    f16*         Xhb = Xh + ((size_t)b*NN + n0)*ND + d0;
    #pragma unroll
    for (int it = 0; it < 4; ++it) {
        int r  = it*16 + (t >> 4);
        int c4 = t & 15;
        float4 v = *(const float4*)(Xb + (size_t)r*ND + c4*4);
        f16x4 h; h[0]=(f16)v.x; h[1]=(f16)v.y; h[2]=(f16)v.z; h[3]=(f16)v.w;
        *(f16x4*)&Xhb[(size_t)r*ND + c4*4] = h;
        *(f16x4*)&T[r][c4*4] = h;
    }
    __syncthreads();
    f16* Xtb = Xt + ((size_t)b*ND + d0)*NN + n0;
    #pragma unroll
    for (int it = 0; it < 2; ++it) {
        int id = it*256 + t;
        int dr = id >> 3;
        int ch = id & 7;
        f16x8 v;
        #pragma unroll
        for (int u = 0; u < 8; ++u) v[u] = T[ch*8+u][dr];
        *(f16x8*)&Xtb[(size_t)dr*NN + ch*8] = v;
    }
}

// ---------------- main flash-attention: 4-wave blocks, frag-order LDS -------
// LDS layouts (16B slots):
//   K:  slot S = kk*128 + j*4 + g    (byte kk*2048 + j*64 + g*16)
//        holds K[j][d = kk*32 + g*8 + i]   (i=0..7)
//   Vt: slot T = dt*64  + c*4 + g    (byte dt*1024 + c*64 + g*16)
//        holds V[j = g*8 + i][d = dt*16 + c]
// Frag reads per MFMA step are contiguous 1KB per wave -> conflict-free.
__global__ __launch_bounds__(256, 2)
void attn4(const f16* __restrict__ Xh, const f16* __restrict__ Xt,
           const int* __restrict__ lenp, float* __restrict__ out)
{
    const int tid  = threadIdx.x;
    const int lane = tid & 63;
    const int w = tid >> 6;
    const int g = lane >> 4;
    const int c = lane & 15;

    // ---- LPT + XCD-paired job mapping ----
    const bool is64 = (lenp[1] == 0);
    long long Lv[NB];
    #pragma unroll
    for (int i = 0; i < NB; ++i) Lv[i] = len_at(lenp, i, is64);
    const int x = blockIdx.x & 7;         // XCD heuristic (blockIdx % 8)
    const int k = blockIdx.x >> 3;        // 0..63
    const int wanted = (k < 32) ? x : (15 - x);
    const int qt = k & 31;
    int bsel = 0; long long Lb = 1;
    #pragma unroll
    for (int bb = 0; bb < NB; ++bb) {
        int rk = 0;
        #pragma unroll
        for (int b2 = 0; b2 < NB; ++b2)
            rk += (Lv[b2] > Lv[bb]) || (Lv[b2] == Lv[bb] && b2 < bb);
        if (rk == wanted) { bsel = bb; Lb = Lv[bb]; }
    }
    const int nt = (int)((Lb + KVB - 1) / KVB);

    __shared__ f16 Kl[2][8192];     // 2 x 16KB
    __shared__ f16 Vl[2][8192];     // 2 x 16KB
    __shared__ f16 Pl[4][16*36];    // per-wave P round-trip, 72B rows

    const char* xhb = (const char*)(Xh + (size_t)bsel*NN*ND);
    const char* xtb = (const char*)(Xt + (size_t)bsel*ND*NN);

    // ---- Q fragments in registers ----
    f16x8 qf[8];
    {
        const char* qp = xhb + (size_t)(qt*QB + w*16 + c)*512 + g*16;
        #pragma unroll
        for (int kk = 0; kk < 8; ++kk) qf[kk] = *(const f16x8*)(qp + kk*64);
    }

    // ---- staging: 4 gll K + 4 gll V per thread per tile ----
    auto stage = [&](int buf, int kv0) {
        char* kb = (char*)&Kl[buf][0];
        char* vb = (char*)&Vl[buf][0];
        #pragma unroll
        for (int it = 0; it < 4; ++it) {
            int S  = it*256 + tid;
            int kk = S >> 7, j = (S >> 2) & 31, gg = S & 3;
            gll16(xhb + (size_t)(kv0 + j)*512 + kk*64 + gg*16, kb + S*16);
        }
        #pragma unroll
        for (int it = 0; it < 4; ++it) {
            int T  = it*256 + tid;
            int dt = T >> 6, cc = (T >> 2) & 15, gg = T & 3;
            gll16(xtb + (size_t)(dt*16 + cc)*4096 + (size_t)(kv0 + gg*8)*2, vb + T*16);
        }
    };

    f32x4 o[16];
    #pragma unroll
    for (int dt = 0; dt < 16; ++dt) o[dt] = (f32x4){0.f,0.f,0.f,0.f};
    float m[4] = {-INFINITY,-INFINITY,-INFINITY,-INFINITY};
    float l[4] = {0.f,0.f,0.f,0.f};

    f16* pw = &Pl[w][0];

    // ---- prologue: tiles 0 and 1 in flight ----
    stage(0, 0);
    if (nt > 1) stage(1, KVB);

    for (int t = 0; t < nt; ++t) {
        const int kv0 = t * KVB;
        const int buf = t & 1;

        if (t + 1 < nt) { asm volatile("s_waitcnt vmcnt(8)" ::: "memory"); }
        else            { asm volatile("s_waitcnt vmcnt(0)" ::: "memory"); }
        __builtin_amdgcn_s_barrier();      // all waves' tile-t slices landed

        const char* kb = (const char*)&Kl[buf][0];
        const char* vb = (const char*)&Vl[buf][0];

        // ---- QK^T: S[16q x 32j] in two 16x16 tiles ----
        f32x4 s0 = (f32x4){0.f,0.f,0.f,0.f};
        f32x4 s1 = (f32x4){0.f,0.f,0.f,0.f};
        #pragma unroll
        for (int kk = 0; kk < 8; ++kk) {
            f16x8 b0 = *(const f16x8*)(kb + kk*2048        + c*64 + g*16);
            f16x8 b1 = *(const f16x8*)(kb + kk*2048 + 1024 + c*64 + g*16);
            s0 = __builtin_amdgcn_mfma_f32_16x16x32_f16(qf[kk], b0, s0, 0, 0, 0);
            s1 = __builtin_amdgcn_mfma_f32_16x16x32_f16(qf[kk], b1, s1, 0, 0, 0);
        }

        const float NEG = -1e30f;
        if (kv0 + c >= Lb)      { s0[0]=NEG; s0[1]=NEG; s0[2]=NEG; s0[3]=NEG; }
        if (kv0 + 16 + c >= Lb) { s1[0]=NEG; s1[1]=NEG; s1[2]=NEG; s1[3]=NEG; }

        // ---- online softmax (rows g*4+r, reduce across 16 lanes) ----
        float mx[4], mn[4], sc[4], p0[4], p1[4], rs[4];
        #pragma unroll
        for (int r = 0; r < 4; ++r) mx[r] = fmaxf(s0[r], s1[r]);
        #pragma unroll
        for (int off = 8; off >= 1; off >>= 1) {
            #pragma unroll
            for (int r = 0; r < 4; ++r)
                mx[r] = fmaxf(mx[r], __shfl_xor(mx[r], off, 64));
        }
        #pragma unroll
        for (int r = 0; r < 4; ++r) {
            mn[r] = fmaxf(m[r], mx[r]);
            sc[r] = __expf(m[r] - mn[r]);
            p0[r] = __expf(s0[r] - mn[r]);
            p1[r] = __expf(s1[r] - mn[r]);
            rs[r] = p0[r] + p1[r];
        }
        #pragma unroll
        for (int off = 8; off >= 1; off >>= 1) {
            #pragma unroll
            for (int r = 0; r < 4; ++r)
                rs[r] += __shfl_xor(rs[r], off, 64);
        }
        bool chg = (sc[0]!=1.f) | (sc[1]!=1.f) | (sc[2]!=1.f) | (sc[3]!=1.f);
        if (__any(chg)) {
            #pragma unroll
            for (int dt = 0; dt < 16; ++dt) {
                o[dt][0]*=sc[0]; o[dt][1]*=sc[1]; o[dt][2]*=sc[2]; o[dt][3]*=sc[3];
            }
        }
        #pragma unroll
        for (int r = 0; r < 4; ++r) { l[r] = l[r]*sc[r] + rs[r]; m[r] = mn[r]; }

        // ---- P round-trip (C-layout -> A-layout), 72B rows ----
        #pragma unroll
        for (int r = 0; r < 4; ++r) {
            pw[(g*4+r)*36 + c]      = (f16)p0[r];
            pw[(g*4+r)*36 + 16 + c] = (f16)p1[r];
        }
        union { f16x4 h[2]; f16x8 v; } pu;
        pu.h[0] = *(const f16x4*)(pw + c*36 + g*8);
        pu.h[1] = *(const f16x4*)(pw + c*36 + g*8 + 4);
        f16x8 pf = pu.v;

        // ---- PV: O[16q x 256d] += P(16x32) x V(32x16) per d-tile ----
        #pragma unroll
        for (int dt = 0; dt < 16; ++dt) {
            f16x8 vf = *(const f16x8*)(vb + dt*1024 + c*64 + g*16);
            o[dt] = __builtin_amdgcn_mfma_f32_16x16x32_f16(pf, vf, o[dt], 0, 0, 0);
        }

        __builtin_amdgcn_s_barrier();      // everyone done reading buf
        if (t + 2 < nt) stage(buf, kv0 + 2*KVB);
    }

    // ---- epilogue ----
    float inv[4];
    #pragma unroll
    for (int r = 0; r < 4; ++r) inv[r] = 1.0f / l[r];
    float* ob = out + ((size_t)bsel*NN + (size_t)(qt*QB + w*16 + g*4))*ND + c;
    #pragma unroll
    for (int r = 0; r < 4; ++r) {
        #pragma unroll
        for (int dt = 0; dt < 16; ++dt)
            ob[(size_t)r*ND + dt*16] = o[dt][r] * inv[r];
    }
}

// ---------------- fallback (round-1 kernel) if ws too small ----------------
__global__ __launch_bounds__(256, 2)
void attn_fb(const float* __restrict__ X,
             const int* __restrict__ lenp,
             float* __restrict__ out)
{
    const int b   = blockIdx.y;
    const int qt  = blockIdx.x;
    const int tid = threadIdx.x;
    const int lane = tid & 63;
    const int w = tid >> 6;
    const int g = lane >> 4;
    const int c = lane & 15;

    const bool is64 = (lenp[1] == 0);
    const long long Lb = len_at(lenp, b, is64);

    __shared__ f16 Kl[KVB][264];
    __shared__ f16 Vt2[ND][40];
    __shared__ f16 Pl[4][16][40];

    const float* Xb = X + (size_t)b * NN * ND;

    f16x8 qf[8];
    {
        const float* qp = Xb + (size_t)(qt*64 + w*16 + c) * ND + g*8;
        #pragma unroll
        for (int kk = 0; kk < 8; ++kk) {
            float4 a = *(const float4*)(qp + kk*32);
            float4 d = *(const float4*)(qp + kk*32 + 4);
            f16x8 v;
            v[0]=(f16)a.x; v[1]=(f16)a.y; v[2]=(f16)a.z; v[3]=(f16)a.w;
            v[4]=(f16)d.x; v[5]=(f16)d.y; v[6]=(f16)d.z; v[7]=(f16)d.w;
            qf[kk] = v;
        }
    }

    f32x4 o[16];
    #pragma unroll
    for (int dt = 0; dt < 16; ++dt) o[dt] = (f32x4){0.f,0.f,0.f,0.f};
    float m[4] = {-INFINITY,-INFINITY,-INFINITY,-INFINITY};
    float lr[4] = {0.f,0.f,0.f,0.f};

    const int ntiles = (int)((Lb + KVB - 1) / KVB);
    for (int t = 0; t < ntiles; ++t) {
        const int kv0 = t * KVB;
        __syncthreads();
        #pragma unroll
        for (int it = 0; it < 8; ++it) {
            int idx4 = it*256 + tid;
            int row  = idx4 >> 6;
            int c4   = idx4 & 63;
            float4 v = *(const float4*)(Xb + (size_t)(kv0 + row)*ND + c4*4);
            f16x4 hh; hh[0]=(f16)v.x; hh[1]=(f16)v.y; hh[2]=(f16)v.z; hh[3]=(f16)v.w;
            *(f16x4*)&Kl[row][c4*4] = hh;
        }
        {
            const float* cp = Xb + (size_t)kv0*ND + tid;
            #pragma unroll
            for (int kq = 0; kq < 8; ++kq) {
                f16x4 hh;
                #pragma unroll
                for (int u = 0; u < 4; ++u) hh[u] = (f16)cp[(size_t)(kq*4+u)*ND];
                *(f16x4*)&Vt2[tid][kq*4] = hh;
            }
        }
        __syncthreads();

        f32x4 s0 = (f32x4){0.f,0.f,0.f,0.f};
        f32x4 s1 = (f32x4){0.f,0.f,0.f,0.f};
        #pragma unroll
        for (int kk = 0; kk < 8; ++kk) {
            f16x8 b0 = *(const f16x8*)&Kl[c     ][kk*32 + g*8];
            f16x8 b1 = *(const f16x8*)&Kl[16 + c][kk*32 + g*8];
            s0 = __builtin_amdgcn_mfma_f32_16x16x32_f16(qf[kk], b0, s0, 0, 0, 0);
            s1 = __builtin_amdgcn_mfma_f32_16x16x32_f16(qf[kk], b1, s1, 0, 0, 0);
        }

        const float NEG = -1e30f;
        if (kv0 + c >= Lb)      { s0[0]=NEG; s0[1]=NEG; s0[2]=NEG; s0[3]=NEG; }
        if (kv0 + 16 + c >= Lb) { s1[0]=NEG; s1[1]=NEG; s1[2]=NEG; s1[3]=NEG; }

        float mx[4], mn[4], sc[4], p0[4], p1[4], rs[4];
        #pragma unroll
        for (int r = 0; r < 4; ++r) mx[r] = fmaxf(s0[r], s1[r]);
        #pragma unroll
        for (int off = 8; off >= 1; off >>= 1) {
            #pragma unroll
            for (int r = 0; r < 4; ++r)
                mx[r] = fmaxf(mx[r], __shfl_xor(mx[r], off, 64));
        }
        #pragma unroll
        for (int r = 0; r < 4; ++r) {
            mn[r] = fmaxf(m[r], mx[r]);
            sc[r] = __expf(m[r] - mn[r]);
            p0[r] = __expf(s0[r] - mn[r]);
            p1[r] = __expf(s1[r] - mn[r]);
            rs[r] = p0[r] + p1[r];
        }
        #pragma unroll
        for (int off = 8; off >= 1; off >>= 1) {
            #pragma unroll
            for (int r = 0; r < 4; ++r)
                rs[r] += __shfl_xor(rs[r], off, 64);
        }
        bool chg = (sc[0]!=1.f) | (sc[1]!=1.f) | (sc[2]!=1.f) | (sc[3]!=1.f);
        if (__any(chg)) {
            #pragma unroll
            for (int dt = 0; dt < 16; ++dt) {
                o[dt][0]*=sc[0]; o[dt][1]*=sc[1]; o[dt][2]*=sc[2]; o[dt][3]*=sc[3];
            }
        }
        #pragma unroll
        for (int r = 0; r < 4; ++r) { lr[r] = lr[r]*sc[r] + rs[r]; m[r] = mn[r]; }

        #pragma unroll
        for (int r = 0; r < 4; ++r) {
            Pl[w][g*4+r][c]      = (f16)p0[r];
            Pl[w][g*4+r][16 + c] = (f16)p1[r];
        }
        f16x8 pf = *(const f16x8*)&Pl[w][c][g*8];

        #pragma unroll
        for (int dt = 0; dt < 16; ++dt) {
            f16x8 vf = *(const f16x8*)&Vt2[dt*16 + c][g*8];
            o[dt] = __builtin_amdgcn_mfma_f32_16x16x32_f16(pf, vf, o[dt], 0, 0, 0);
        }
    }

    float inv[4];
    #pragma unroll
    for (int r = 0; r < 4; ++r) inv[r] = 1.0f / lr[r];
    float* ob = out + ((size_t)b*NN + (size_t)(qt*64 + w*16 + g*4))*ND + c;
    #pragma unroll
    for (int r = 0; r < 4; ++r) {
        #pragma unroll
        for (int dt = 0; dt < 16; ++dt)
            ob[(size_t)r*ND + dt*16] = o[dt][r] * inv[r];
    }
}

extern "C" void kernel_launch(void* const* d_in, const int* in_sizes, int n_in,
                              void* d_out, int out_size, void* d_ws, size_t ws_size,
                              hipStream_t stream) {
    const float* X    = (const float*)d_in[0];
    const int*   lenp = (const int*)d_in[1];
    float*       out  = (float*)d_out;

    const size_t need = (size_t)NB * NN * ND * 2 /*f16*/ * 2 /*Xh+Xt*/;
    if (ws_size >= need) {
        f16* Xh = (f16*)d_ws;
        f16* Xt = Xh + (size_t)NB * NN * ND;
        hipLaunchKernelGGL(prep, dim3(NN/64, ND/64, NB), dim3(256), 0, stream, X, Xh, Xt);
        hipLaunchKernelGGL(attn4, dim3(512), dim3(256), 0, stream, Xh, Xt, lenp, out);
    } else {
        hipLaunchKernelGGL(attn_fb, dim3(NN/64, NB), dim3(256), 0, stream, X, lenp, out);
    }
}